// Round 1
// baseline (13.097 us; speedup 1.0000x reference)
//
#include <hip/hip_runtime.h>
#include <math.h>

// Problem constants (from reference): forecast (32,20,96,96) f32, truth (32,96,96) f32
#define M_ENS 20
#define HW 9216          // 96*96
#define BHW 294912       // 32*96*96
#define BLOCK 256
#define NBLOCKS ((BHW + BLOCK - 1) / BLOCK)   // 1152

__device__ __forceinline__ void block_reduce2(float& a, float& b) {
    __shared__ float s1[BLOCK];
    __shared__ float s2[BLOCK];
    int tid = threadIdx.x;
    s1[tid] = a; s2[tid] = b;
    __syncthreads();
    for (int off = BLOCK / 2; off > 0; off >>= 1) {
        if (tid < off) { s1[tid] += s1[tid + off]; s2[tid] += s2[tid + off]; }
        __syncthreads();
    }
    a = s1[0]; b = s2[0];
}

__global__ void __launch_bounds__(BLOCK)
crps_partial_kernel(const float* __restrict__ forecast,
                    const float* __restrict__ truth,
                    float* __restrict__ partial) {
    int pix = blockIdx.x * BLOCK + threadIdx.x;
    float crps = 0.0f;
    float pen  = 0.0f;
    if (pix < BHW) {
        int b  = pix / HW;
        int hw = pix - b * HW;
        const float* fp = forecast + (size_t)b * (M_ENS * HW) + hw;

        float x[M_ENS];
        #pragma unroll
        for (int e = 0; e < M_ENS; ++e) x[e] = fp[e * HW];
        float y = truth[pix];

        float dxy = 0.0f, sum = 0.0f;
        #pragma unroll
        for (int e = 0; e < M_ENS; ++e) {
            dxy += fabsf(x[e] - y);
            sum += x[e];
        }

        // upper-triangle pair sum; full m^2 pair-sum (diag=0) is 2x this
        float tri = 0.0f;
        #pragma unroll
        for (int i = 0; i < M_ENS; ++i) {
            #pragma unroll
            for (int j = i + 1; j < M_ENS; ++j) {
                tri += fabsf(x[i] - x[j]);
            }
        }

        float mean = sum * (1.0f / M_ENS);
        float var = 0.0f;
        #pragma unroll
        for (int e = 0; e < M_ENS; ++e) {
            float d = x[e] - mean;
            var += d * d;
        }
        float stdv = sqrtf(var * (1.0f / (M_ENS - 1)));   // ddof=1
        float ks = 3.3f * stdv;

        #pragma unroll
        for (int e = 0; e < M_ENS; ++e) {
            float dev = fabsf(x[e] - mean);
            float p = dev - ks;
            pen += (p > 0.0f) ? p : 0.0f;
        }

        float dxx = (2.0f * tri) * (1.0f / (M_ENS * M_ENS));  // includes zero diagonal
        crps = dxy * (1.0f / M_ENS) - 0.5f * dxx;
    }

    block_reduce2(crps, pen);
    if (threadIdx.x == 0) {
        partial[blockIdx.x] = crps;
        partial[NBLOCKS + blockIdx.x] = pen;
    }
}

__global__ void __launch_bounds__(BLOCK)
crps_final_kernel(const float* __restrict__ partial, float* __restrict__ out) {
    float c = 0.0f, p = 0.0f;
    for (int i = threadIdx.x; i < NBLOCKS; i += BLOCK) {
        c += partial[i];
        p += partial[NBLOCKS + i];
    }
    block_reduce2(c, p);
    if (threadIdx.x == 0) {
        const float lambda = 0.02f;
        out[0] = c * (1.0f / BHW) + lambda * p * (1.0f / ((float)BHW * M_ENS));
    }
}

extern "C" void kernel_launch(void* const* d_in, const int* in_sizes, int n_in,
                              void* d_out, int out_size, void* d_ws, size_t ws_size,
                              hipStream_t stream) {
    const float* forecast = (const float*)d_in[0];
    const float* truth    = (const float*)d_in[1];
    float* out = (float*)d_out;
    float* partial = (float*)d_ws;   // 2 * NBLOCKS floats

    crps_partial_kernel<<<NBLOCKS, BLOCK, 0, stream>>>(forecast, truth, partial);
    crps_final_kernel<<<1, BLOCK, 0, stream>>>(partial, out);
}